// Round 8
// baseline (127.162 us; speedup 1.0000x reference)
//
#include <hip/hip_runtime.h>

typedef unsigned short ushort_t;
typedef __attribute__((ext_vector_type(8))) short short8;
typedef __attribute__((ext_vector_type(4))) short short4v;
typedef __attribute__((ext_vector_type(2))) float float2v;
typedef __attribute__((ext_vector_type(4))) float float4v;

#define Bn 32
#define Nn 2048
#define Cn 8
#define Fn 128
#define On 128
#define AGGK 392   // padded agg row stride in shorts (784 B = 49 x 16 B)
#define P1ROWS 8   // rows per pass-1 block
#define P2ROWS 64  // rows per pass-2 block

// float -> bf16 bits, round-to-nearest-even
__device__ __forceinline__ ushort_t f2bf(float x) {
  unsigned u = __float_as_uint(x);
  u += 0x7fffu + ((u >> 16) & 1u);
  return (ushort_t)(u >> 16);
}

// Pack concat(w_t, w_r, w_l) in MFMA B-fragment order:
// fragment q (0..7), step ks (0..11): element ((q*12+ks)*64 + lane)*8 + j
// holds W[k][col] with col = q*16 + (lane&15), k = (lane>>4)*8 + ks*32 + j.
__global__ void prep_w_kernel(const float* __restrict__ w_t,
                              const float* __restrict__ w_l,
                              const float* __restrict__ w_r,
                              ushort_t* __restrict__ wsw) {
  int t = blockIdx.x * blockDim.x + threadIdx.x; // one short8 per thread
  if (t >= 6144) return;                         // 6144*8 = 49152 elements
  int lane = t & 63;
  int r = t >> 6;  // 0..95
  int ks = r % 12;
  int q = r / 12;  // 0..7
  int col = q * 16 + (lane & 15);
  int kbase = ((lane >> 4) * 8) + ks * 32;
  ushort_t* dst = wsw + (size_t)t * 8;
#pragma unroll
  for (int j = 0; j < 8; ++j) {
    int k = kbase + j;
    const float* src = (k < Fn) ? w_t : (k < 2 * Fn) ? w_r : w_l;
    int f = k & (Fn - 1);
    dst[j] = f2bf(src[f * On + col]);
  }
}

// ---------------- Pass 1: gather + combine -> agg[row][392] (bf16) ----------
// No per-tile barriers: one thread owns one (row, float4-chunk); 9 independent
// loads -> packed-FMA combine -> 24 B of stores. Latency hidden by pure TLP.
__global__ __launch_bounds__(256)
void pass1_kernel(const float* __restrict__ nodes,
                  const int* __restrict__ children,
                  ushort_t* __restrict__ agg) {
  __shared__ int ch_lds[P1ROWS * Cn];
  __shared__ float cf_lds[P1ROWS * 16];

  const int tid = threadIdx.x;
  // XCD swizzle for 8192 blocks: round-robin %8 => XCD k owns sb range
  // [k*1024,(k+1)*1024) = rows [k*8192,(k+1)*8192) = batches 4k..4k+3
  // (4 MB of nodes -> its 4 MiB L2).  NOTE: shift must be log2(8192/8)=10.
  const int sb = ((blockIdx.x & 7) << 10) | (blockIdx.x >> 3);
  const int rb0 = sb * P1ROWS;

  if (tid < P1ROWS * Cn / 4)
    ((int4*)ch_lds)[tid] = ((const int4*)(children + (size_t)rb0 * Cn))[tid];
  __syncthreads();

  if (tid < P1ROWS) {  // one thread computes one row's coefficients
    const int* ch = ch_lds + tid * Cn;
    int idx[Cn];
#pragma unroll
    for (int c = 0; c < Cn; ++c) idx[c] = ch[c];
    int ns = 0;
#pragma unroll
    for (int c = 0; c < Cn; ++c) ns += (idx[c] != 0);
    const float denom = (ns > 1) ? (float)(ns - 1) : 1.0f;
#pragma unroll
    for (int c = 0; c < Cn; ++c) {
      float m = (idx[c] != 0) ? 1.0f : 0.0f;
      float cr0 = (ns == 1) ? ((c == 0) ? 0.5f : 0.0f) : ((float)c / denom);
      float cr = cr0 * m;
      cf_lds[tid * 16 + 2 * c] = cr;
      cf_lds[tid * 16 + 2 * c + 1] = (1.0f - cr) * m;
    }
  }
  __syncthreads();

  const int grp = tid >> 5;  // row within block
  const int ln = tid & 31;   // float4 chunk of F
  const int g = rb0 + grp;
  const int base_row = g & ~(Nn - 1);

  // self load (independent) + gathers
  const float4v sv = *((const float4v*)(nodes + (size_t)g * Fn) + ln);

  float4v gv[Cn];
#pragma unroll
  for (int c = 0; c < Cn; ++c) {
    // clamp: replay-safe even with poisoned children; no-op for valid inputs
    const int r = base_row + (ch_lds[grp * Cn + c] & (Nn - 1));
    gv[c] = *((const float4v*)(nodes + (size_t)r * Fn) + ln);
  }

  // (r,l) in float2 lanes -> v_pk_fma_f32
  float2v rl0 = {0.f, 0.f}, rl1 = {0.f, 0.f}, rl2 = {0.f, 0.f}, rl3 = {0.f, 0.f};
#pragma unroll
  for (int c = 0; c < Cn; ++c) {
    const float2v cc = {cf_lds[grp * 16 + 2 * c], cf_lds[grp * 16 + 2 * c + 1]};
    const float4v v = gv[c];
    rl0 += (float2v){v.x, v.x} * cc;
    rl1 += (float2v){v.y, v.y} * cc;
    rl2 += (float2v){v.z, v.z} * cc;
    rl3 += (float2v){v.w, v.w} * cc;
  }

  ushort_t* arow = agg + (size_t)g * AGGK;
  short4v ps = {(short)f2bf(sv.x), (short)f2bf(sv.y),
                (short)f2bf(sv.z), (short)f2bf(sv.w)};
  short4v pr = {(short)f2bf(rl0.x), (short)f2bf(rl1.x),
                (short)f2bf(rl2.x), (short)f2bf(rl3.x)};
  short4v pl = {(short)f2bf(rl0.y), (short)f2bf(rl1.y),
                (short)f2bf(rl2.y), (short)f2bf(rl3.y)};
  *(short4v*)(arow + ln * 4) = ps;
  *(short4v*)(arow + Fn + ln * 4) = pr;
  *(short4v*)(arow + 2 * Fn + ln * 4) = pl;
}

// ---------------- Pass 2: dense GEMM out = relu(agg @ W + b) ----------------
// Block: 64 rows x 128 cols; A tile (64 x 392 shorts, incl. pad) staged to LDS
// once; each wave owns 32 cols with 24 B-frags in regs; 96 MFMAs per wave.
__global__ __launch_bounds__(256)
void pass2_kernel(const ushort_t* __restrict__ agg,
                  const ushort_t* __restrict__ wsw,
                  const float* __restrict__ bias,
                  float* __restrict__ out) {
  __shared__ __align__(16) ushort_t tile[P2ROWS * AGGK];  // 50176 B

  const int tid = threadIdx.x;
  const int rb0 = blockIdx.x * P2ROWS;
  const int lane = tid & 63;
  const int wave = tid >> 6;
  const int l15 = lane & 15;
  const int quad = lane >> 4;

  // Stage A tile: 64*49 = 3136 16-B units = 12 x 256 + 64.
  const short8* gsrc = (const short8*)(agg + (size_t)rb0 * AGGK);
  short8 sreg[12];
#pragma unroll
  for (int it = 0; it < 12; ++it) sreg[it] = gsrc[it * 256 + tid];
  short8 srem;
  if (tid < 64) srem = gsrc[3072 + tid];

  short8* ldst = (short8*)tile;
#pragma unroll
  for (int it = 0; it < 12; ++it) ldst[it * 256 + tid] = sreg[it];
  if (tid < 64) ldst[3072 + tid] = srem;

  // B fragments (issued before barrier; consumed after — latency hidden)
  short8 bfrag[2][12];
#pragma unroll
  for (int ct = 0; ct < 2; ++ct)
#pragma unroll
    for (int ks = 0; ks < 12; ++ks)
      bfrag[ct][ks] =
          ((const short8*)wsw)[(((wave * 2 + ct) * 12) + ks) * 64 + lane];

  const int col0 = wave * 32 + l15;
  const float bb0 = bias[col0];
  const float bb1 = bias[col0 + 16];

  __syncthreads();

#pragma unroll
  for (int st4 = 0; st4 < 4; ++st4) {
    const ushort_t* ar = tile + (st4 * 16 + l15) * AGGK + quad * 8;
    float4v acc0 = {0.f, 0.f, 0.f, 0.f};
    float4v acc1 = {0.f, 0.f, 0.f, 0.f};
#pragma unroll
    for (int ks = 0; ks < 12; ++ks) {
      short8 af = *(const short8*)(ar + ks * 32);
      acc0 = __builtin_amdgcn_mfma_f32_16x16x32_bf16(af, bfrag[0][ks], acc0, 0, 0, 0);
      acc1 = __builtin_amdgcn_mfma_f32_16x16x32_bf16(af, bfrag[1][ks], acc1, 0, 0, 0);
    }
    const int grow = rb0 + st4 * 16 + quad * 4;
#pragma unroll
    for (int r2 = 0; r2 < 4; ++r2) {
      out[(size_t)(grow + r2) * On + col0] = fmaxf(acc0[r2] + bb0, 0.f);
      out[(size_t)(grow + r2) * On + col0 + 16] = fmaxf(acc1[r2] + bb1, 0.f);
    }
  }
}

extern "C" void kernel_launch(void* const* d_in, const int* in_sizes, int n_in,
                              void* d_out, int out_size, void* d_ws, size_t ws_size,
                              hipStream_t stream) {
  const float* nodes = (const float*)d_in[0];
  const int* children = (const int*)d_in[1];
  const float* w_t = (const float*)d_in[2];
  const float* w_l = (const float*)d_in[3];
  const float* w_r = (const float*)d_in[4];
  const float* bias = (const float*)d_in[5];
  float* out = (float*)d_out;

  ushort_t* agg = (ushort_t*)d_ws;  // 65536 * 392 * 2 B = 49 MiB
  ushort_t* wsw = (ushort_t*)((char*)d_ws + ((size_t)64 << 20));  // 96 KiB

  prep_w_kernel<<<24, 256, 0, stream>>>(w_t, w_l, w_r, wsw);
  pass1_kernel<<<(Bn * Nn) / P1ROWS, 256, 0, stream>>>(nodes, children, agg);
  pass2_kernel<<<(Bn * Nn) / P2ROWS, 256, 0, stream>>>(agg, wsw, bias, out);
}